// Round 10
// baseline (127.477 us; speedup 1.0000x reference)
//
#include <hip/hip_runtime.h>

#define B_SZ 8
#define N_SZ 65536
#define C_SZ 128
#define K_SZ 15
#define KPAD 16
#define THREADS 256
#define ROWS 4                         // c-rows per wave
#define C_BLK 16                       // c-rows per block (4 waves x 4)
#define G 8                            // c-groups (C_SZ / C_BLK)
#define S_SPANS 32                     // n-spans per batch
#define NSPAN 2048                     // N_SZ / S_SPANS
#define WSTEPS (NSPAN / 64)            // 32 steps of 64 n (one n per lane)
#define PART_PER_BLK (C_BLK * K_SZ)    // 240
#define NBLKS (B_SZ * S_SPANS * G)     // 2048
#define INV_KP_EXTENT (1.0f / 0.48f)

// ---------- pre-pass: w[b][n][k(16 padded)] fp32, 64 B contiguous per n ------
__global__ __launch_bounds__(THREADS) void kpconv_weights_t(
    const float* __restrict__ p, const float* __restrict__ kp,
    float* __restrict__ wglob) {
  __shared__ float kps[K_SZ * 3];
  const int tid = threadIdx.x;
  if (tid < K_SZ * 3) kps[tid] = kp[tid];
  __syncthreads();

  const size_t n = (size_t)blockIdx.x * THREADS + tid;   // over B*N
  const float px = p[n * 3 + 0], py = p[n * 3 + 1], pz = p[n * 3 + 2];
  float w[KPAD];
#pragma unroll
  for (int k = 0; k < K_SZ; ++k) {
    const float dx = px - kps[3 * k + 0];
    const float dy = py - kps[3 * k + 1];
    const float dz = pz - kps[3 * k + 2];
    const float d = sqrtf(fmaf(dx, dx, fmaf(dy, dy, dz * dz)));
    w[k] = fmaxf(1.0f - d * INV_KP_EXTENT, 0.0f);
  }
  w[15] = 0.0f;
  float4* dst = reinterpret_cast<float4*>(wglob) + n * 4;
  dst[0] = make_float4(w[0], w[1], w[2], w[3]);
  dst[1] = make_float4(w[4], w[5], w[6], w[7]);
  dst[2] = make_float4(w[8], w[9], w[10], w[11]);
  dst[3] = make_float4(w[12], w[13], w[14], w[15]);
}

// compile-time component select from a float4[4] quad (k_ is unrolled-const)
#define WELT(q, kk) (((kk) & 3) == 0 ? q[(kk) >> 2].x : ((kk) & 3) == 1 ? q[(kk) >> 2].y : ((kk) & 3) == 2 ? q[(kk) >> 2].z : q[(kk) >> 2].w)

// ---------- main: barrier-free, LDS-free streaming; one n per lane -----------
__global__ __launch_bounds__(THREADS, 2) void kpconv_main_st(
    const float* __restrict__ x, const float* __restrict__ wglob,
    float* __restrict__ part) {
  const int tid = threadIdx.x;
  const int blk = blockIdx.x;            // (b*S_SPANS + s)*G + cg  (cg innermost)
  const int cg = blk % G;
  const int bs = blk / G;
  const int b  = bs / S_SPANS;
  const int s  = bs % S_SPANS;
  const int lane = tid & 63;
  const int wid  = tid >> 6;
  const int nbase = s * NSPAN;

  const float* xl = x + (size_t)b * C_SZ * N_SZ
                      + (size_t)(cg * C_BLK + wid * ROWS) * N_SZ + nbase + lane;
  const float4* wl = reinterpret_cast<const float4*>(wglob)
                      + ((size_t)b * N_SZ + nbase + lane) * 4;

  float acc[ROWS][K_SZ];
#pragma unroll
  for (int r = 0; r < ROWS; ++r)
#pragma unroll
    for (int k = 0; k < K_SZ; ++k) acc[r][k] = 0.0f;

#define LOADW(dst, t)                                                         \
  do {                                                                        \
    dst[0] = wl[(size_t)(t) * 256 + 0];                                       \
    dst[1] = wl[(size_t)(t) * 256 + 1];                                       \
    dst[2] = wl[(size_t)(t) * 256 + 2];                                       \
    dst[3] = wl[(size_t)(t) * 256 + 3];                                       \
  } while (0)

#define LOADX(dst, t)                                                         \
  do {                                                                        \
    _Pragma("unroll")                                                         \
    for (int r_ = 0; r_ < ROWS; ++r_)                                         \
      dst[r_] = xl[(size_t)r_ * N_SZ + (t) * 64];                             \
  } while (0)

#define DOFMA(wq, xv)                                                         \
  do {                                                                        \
    _Pragma("unroll")                                                         \
    for (int k_ = 0; k_ < K_SZ; ++k_) {                                       \
      const float wk_ = WELT(wq, k_);                                         \
      _Pragma("unroll")                                                       \
      for (int r_ = 0; r_ < ROWS; ++r_)                                       \
        acc[r_][k_] = fmaf(wk_, xv[r_], acc[r_][k_]);                         \
    }                                                                         \
  } while (0)

  float4 wA[4], wB[4];
  float xA[ROWS], xB[ROWS];
  LOADW(wA, 0);
  LOADX(xA, 0);

  for (int t = 0; t < WSTEPS; t += 2) {
    LOADW(wB, t + 1);            // t+1 <= 31 always (WSTEPS even)
    LOADX(xB, t + 1);
    DOFMA(wA, xA);
    if (t + 2 < WSTEPS) {
      LOADW(wA, t + 2);
      LOADX(xA, t + 2);
    }
    DOFMA(wB, xB);
  }

  // reduce acc[r][k] across 64 lanes (n); lane k keeps k; lanes 0..14 store.
  float* pout = part + (size_t)blk * PART_PER_BLK + wid * (ROWS * K_SZ);
#pragma unroll
  for (int r = 0; r < ROWS; ++r) {
    float keep = 0.0f;
#pragma unroll
    for (int k = 0; k < K_SZ; ++k) {
      float v = acc[r][k];
      v += __shfl_xor(v, 1);
      v += __shfl_xor(v, 2);
      v += __shfl_xor(v, 4);
      v += __shfl_xor(v, 8);
      v += __shfl_xor(v, 16);
      v += __shfl_xor(v, 32);
      if (lane == k) keep = v;
    }
    if (lane < K_SZ) pout[r * K_SZ + lane] = keep;
  }
}

// ---------- fallback main (round-7 structure, in-loop weight compute) ---------
__global__ __launch_bounds__(THREADS, 2) void kpconv_main_fb(
    const float* __restrict__ p, const float* __restrict__ x,
    const float* __restrict__ kp, float* __restrict__ part) {
  __shared__ float wt[2][K_SZ][256];
  __shared__ float kps[K_SZ * 3];

  const int tid = threadIdx.x;
  const int blk = blockIdx.x;            // (b*S_SPANS + s)*G + cg
  const int cg = blk % G;
  const int bs = blk / G;
  const int b  = bs / S_SPANS;
  const int s  = bs % S_SPANS;
  const int nbase = s * NSPAN;

  if (tid < K_SZ * 3) kps[tid] = kp[tid];

  const int lane = tid & 63;
  const int wid  = tid >> 6;

  const float* pb = p + (size_t)b * N_SZ * 3 + (size_t)nbase * 3;
  const float* xrow0 = x + (size_t)b * C_SZ * N_SZ
                         + (size_t)(cg * C_BLK + wid * ROWS) * N_SZ + nbase;

  float acc[ROWS][K_SZ];
#pragma unroll
  for (int r = 0; r < ROWS; ++r)
#pragma unroll
    for (int k = 0; k < K_SZ; ++k) acc[r][k] = 0.0f;

#define FB_LOAD_X(dst, toff)                                                  \
  do {                                                                        \
    _Pragma("unroll")                                                         \
    for (int r_ = 0; r_ < ROWS; ++r_)                                         \
      dst[r_] = *reinterpret_cast<const float4*>(                             \
          xrow0 + (size_t)r_ * N_SZ + (toff) * 256 + 4 * lane);               \
  } while (0)

#define FB_FILL_WT(bufi, toff)                                                \
  do {                                                                        \
    const int nl_ = (toff) * 256 + tid;                                       \
    const float px_ = pb[3 * nl_ + 0];                                        \
    const float py_ = pb[3 * nl_ + 1];                                        \
    const float pz_ = pb[3 * nl_ + 2];                                        \
    _Pragma("unroll")                                                         \
    for (int k_ = 0; k_ < K_SZ; ++k_) {                                       \
      const float dx_ = px_ - kps[3 * k_ + 0];                                \
      const float dy_ = py_ - kps[3 * k_ + 1];                                \
      const float dz_ = pz_ - kps[3 * k_ + 2];                                \
      const float d_ = sqrtf(fmaf(dx_, dx_, fmaf(dy_, dy_, dz_ * dz_)));      \
      wt[bufi][k_][tid] = fmaxf(1.0f - d_ * INV_KP_EXTENT, 0.0f);             \
    }                                                                         \
  } while (0)

#define FB_DO_FMA(xr, bufi)                                                   \
  do {                                                                        \
    _Pragma("unroll")                                                         \
    for (int k_ = 0; k_ < K_SZ; ++k_) {                                       \
      const float4 wq_ = *reinterpret_cast<const float4*>(&wt[bufi][k_][4 * lane]); \
      _Pragma("unroll")                                                       \
      for (int r_ = 0; r_ < ROWS; ++r_)                                       \
        acc[r_][k_] = fmaf(wq_.x, xr[r_].x,                                   \
                      fmaf(wq_.y, xr[r_].y,                                   \
                      fmaf(wq_.z, xr[r_].z,                                   \
                      fmaf(wq_.w, xr[r_].w, acc[r_][k_]))));                  \
    }                                                                         \
  } while (0)

  float4 xA[ROWS], xB[ROWS];
  __syncthreads();
  FB_FILL_WT(0, 0);
  FB_LOAD_X(xA, 0);
  __syncthreads();

  const int steps = NSPAN / 256;
  for (int t = 0; t < steps; t += 2) {
    if (t + 1 < steps) {
      FB_LOAD_X(xB, t + 1);
      FB_FILL_WT(1, t + 1);
    }
    FB_DO_FMA(xA, 0);
    __syncthreads();
    if (t + 1 < steps) {
      if (t + 2 < steps) {
        FB_LOAD_X(xA, t + 2);
        FB_FILL_WT(0, t + 2);
      }
      FB_DO_FMA(xB, 1);
      __syncthreads();
    }
  }

  float* pout = part + (size_t)blk * PART_PER_BLK + wid * (ROWS * K_SZ);
#pragma unroll
  for (int r = 0; r < ROWS; ++r) {
    float keep = 0.0f;
#pragma unroll
    for (int k = 0; k < K_SZ; ++k) {
      float v = acc[r][k];
      v += __shfl_xor(v, 1);
      v += __shfl_xor(v, 2);
      v += __shfl_xor(v, 4);
      v += __shfl_xor(v, 8);
      v += __shfl_xor(v, 16);
      v += __shfl_xor(v, 32);
      if (lane == k) keep = v;
    }
    if (lane < K_SZ) pout[r * K_SZ + lane] = keep;
  }
}

// part[(b*S_SPANS+s)*G + cg][wid][r][k];  c = cg*16 + wid*4 + r.
__global__ __launch_bounds__(C_SZ) void kpconv_reduce_gemm(
    const float* __restrict__ part, const float* __restrict__ W,
    float* __restrict__ out) {
  const int k = blockIdx.x;    // 0..14
  const int b = blockIdx.y;    // 0..7
  const int tid = threadIdx.x; // c
  __shared__ float row[C_SZ];

  const int cg = tid >> 4, wid = (tid >> 2) & 3, r = tid & 3;
  const size_t base = ((size_t)(b * S_SPANS) * G + cg) * PART_PER_BLK
                    + wid * (ROWS * K_SZ) + r * K_SZ + k;
  float sum = 0.0f;
  for (int ss = 0; ss < S_SPANS; ++ss)
    sum += part[base + (size_t)ss * G * PART_PER_BLK];
  row[tid] = sum;
  __syncthreads();

  float acc = 0.0f;
  const float* Wk = W + (size_t)k * C_SZ * C_SZ;
#pragma unroll 8
  for (int c = 0; c < C_SZ; ++c) acc += row[c] * Wk[(size_t)c * C_SZ + tid];
  atomicAdd(&out[b * C_SZ + tid], acc);
}

extern "C" void kernel_launch(void* const* d_in, const int* in_sizes, int n_in,
                              void* d_out, int out_size, void* d_ws, size_t ws_size,
                              hipStream_t stream) {
  const float* p  = (const float*)d_in[0];
  const float* x  = (const float*)d_in[1];
  const float* w  = (const float*)d_in[2];
  const float* kp = (const float*)d_in[3];
  float* out  = (float*)d_out;
  float* part = (float*)d_ws;

  const size_t part_bytes = (size_t)NBLKS * PART_PER_BLK * sizeof(float);   // ~1.97 MB
  const size_t walign = (part_bytes + 255) & ~(size_t)255;
  const size_t wbytes = (size_t)B_SZ * N_SZ * KPAD * sizeof(float);         // 33.55 MB

  (void)hipMemsetAsync(d_out, 0, (size_t)out_size * sizeof(float), stream);
  if (ws_size >= walign + wbytes) {
    float* wglob = (float*)((char*)d_ws + walign);
    kpconv_weights_t<<<dim3(B_SZ * N_SZ / THREADS), THREADS, 0, stream>>>(p, kp, wglob);
    kpconv_main_st<<<dim3(NBLKS), THREADS, 0, stream>>>(x, wglob, part);
  } else {
    kpconv_main_fb<<<dim3(NBLKS), THREADS, 0, stream>>>(p, x, kp, part);
  }
  kpconv_reduce_gemm<<<dim3(K_SZ, B_SZ), C_SZ, 0, stream>>>(part, w, out);
}